// Round 1
// baseline (305.768 us; speedup 1.0000x reference)
//
#include <hip/hip_runtime.h>
#include <math.h>

#define CB 512
#define CS 1024
#define CT 50
#define PF 4   // x-prefetch depth / renorm cadence

typedef float v2f __attribute__((ext_vector_type(2)));

#if __has_builtin(__builtin_amdgcn_permlane16_swap)
#define HAVE_PL16 1
#else
#define HAVE_PL16 0
#endif
#if __has_builtin(__builtin_amdgcn_permlane32_swap)
#define HAVE_PL32 1
#else
#define HAVE_PL32 0
#endif

__global__ void zero_out_kernel(float* out) { out[0] = 0.0f; }

__device__ __forceinline__ int lane0_bits(float v) {
    return __builtin_amdgcn_readlane(__float_as_int(v), 0);
}

// generic DPP mov: quad_perm 0xB1 = xor1, 0x4E = xor2; row_ror:4 = 0x124, row_ror:8 = 0x128
template <int CTRL>
__device__ __forceinline__ float dppmov(float v) {
    return __int_as_float(__builtin_amdgcn_update_dpp(
        0, __float_as_int(v), CTRL, 0xf, 0xf, false));
}

// After call: {a,b} hold {v[l ^ F32], v[l ^ (32^F32)]} with F32 = HAVE_PL32 ? (l&32) : 0.
__device__ __forceinline__ void expand32(float &a, float &b, int lane) {
#if HAVE_PL32
    (void)lane;
    auto r = __builtin_amdgcn_permlane32_swap(__float_as_uint(a), __float_as_uint(a),
                                              false, false);
    a = __uint_as_float(r[0]);
    b = __uint_as_float(r[1]);
#else
    b = __int_as_float(__builtin_amdgcn_ds_bpermute((lane ^ 32) << 2,
                                                    __float_as_int(a)));
#endif
}

// After call: {a,b} hold {v[l ^ F16], v[l ^ (16^F16)]} with F16 = HAVE_PL16 ? (l&16) : 0.
__device__ __forceinline__ void expand16(float &a, float &b, int lane) {
    (void)lane;
#if HAVE_PL16
    auto r = __builtin_amdgcn_permlane16_swap(__float_as_uint(a), __float_as_uint(a),
                                              false, false);
    a = __uint_as_float(r[0]);
    b = __uint_as_float(r[1]);
#else
    b = __int_as_float(__builtin_amdgcn_ds_swizzle(__float_as_int(a), 0x401F)); // xor16
#endif
}

__global__ __launch_bounds__(128, 1) void crf_scan_kernel(
    const float* __restrict__ scores,    // (B,S,T)
    const int*   __restrict__ tags,      // (B,S)
    const int*   __restrict__ mask,      // (B,S)
    const float* __restrict__ trans,     // (T,T)
    const float* __restrict__ start_tr,  // (T)
    const float* __restrict__ end_tr,    // (T)
    float* __restrict__ out)             // scalar
{
    const int b    = blockIdx.x;
    const int tid  = threadIdx.x;
    const int w    = tid >> 6;           // wave 0 = forward, wave 1 = backward
    const int lane = tid & 63;
    const int xl   = (lane < CT) ? lane : 0;
    const bool sel4 = (lane & 4) != 0;
    const bool sel8 = (lane & 8) != 0;

    __shared__ __attribute__((aligned(16))) float sTrans[CT * CT];
    __shared__ float sA[64];
    __shared__ float sB[64];
    __shared__ float sLZ[2], sN[2];

    for (int k = tid; k < CT * CT; k += 128) sTrans[k] = trans[k];
    __syncthreads();

    // ---- per-lane fragment layout (LDS-free step) ----
    // Gather class of lane l: {i : i[3:2] == l[3:2]}  (16 inputs, butterfly over
    // masks 32,16,1,2 — all VALU). Outputs of lane l: s = sbase + 4u, u=0..3,
    // sbase = 16*(l>>4) + (l&3). Partials for output s live on the stride-4
    // in-row class {16h + q + 4j} whose gather classes partition all inputs;
    // reduced with row_ror:4 / row_ror:8 rotation-adds. Selecting u = l[3:2]
    // afterwards leaves the state at identity layout (lane l holds out[l]).
    const int F16   = HAVE_PL16 ? (lane & 16) : 0;
    const int F32   = HAVE_PL32 ? (lane & 32) : 0;
    const int sbase = 16 * (lane >> 4) + (lane & 3);

    // coeff(i,s): fwd = exp(trans[i][s]); bwd = exp(trans[s][i]); pads exactly 0.
    v2f EC0[16], EC1[16];
    #pragma unroll
    for (int k = 0; k < 16; ++k) {
        const int i = lane
            ^ ((k & 1) ? (32 ^ F32) : F32)
            ^ ((k & 2) ? (16 ^ F16) : F16)
            ^ ((k & 4) ? 1 : 0)
            ^ ((k & 8) ? 2 : 0);
        float e[4];
        #pragma unroll
        for (int u = 0; u < 4; ++u) {
            const int s = sbase + 4 * u;
            e[u] = (i < CT && s < CT)
                 ? __expf(w == 0 ? sTrans[i * CT + s] : sTrans[s * CT + i])
                 : 0.f;
        }
        EC0[k] = (v2f){e[0], e[1]};
        EC1[k] = (v2f){e[2], e[3]};
    }

    // sequence length (prefix mask)
    const int* mrow = mask + (size_t)b * CS;
    int len = 0;
    for (int t = lane; t < CS; t += 64) len += mrow[t];
    #pragma unroll
    for (int off = 32; off; off >>= 1) len += __shfl_xor(len, off);

    const float* srow = scores + (size_t)b * CS * CT;
    const float* sx   = srow + xl;

    const int tm    = (len - 1) >> 1;
    const int count = (w == 0) ? tm : ((len >= 2) ? (len - 2 - tm) : 0);
    const int base  = (w == 0) ? 1 : (len - 2);
    const int dir   = (w == 0) ? 1 : -1;

    // linear-domain state; pad lanes (state>=50) exactly 0
    float st;
    if (w == 0) {
        st = (lane < CT) ? __expf(start_tr[lane] + sx[0]) : 0.f;
    } else {
        st = (lane < CT)
            ? ((len >= 2) ? __expf(end_tr[lane] + sx[(size_t)(len - 1) * CT])
                          : __expf(end_tr[lane]))
            : 0.f;
    }
    int kexp = 0;

    #define MAC(k, gk, suf)                                                 \
    {                                                                       \
        const v2f t2 = {gk, gk};                                            \
        a0##suf = __builtin_elementwise_fma(t2, EC0[k], a0##suf);           \
        a1##suf = __builtin_elementwise_fma(t2, EC1[k], a1##suf);           \
    }

    // One step, fully in-register: butterfly all-gather (permlane32/16 swap +
    // quad_perm), 2x8-deep packed FMA chains, rotation reduce, select, scale.
    #define STEP(EX)                                                        \
    {                                                                       \
        float g0 = st, g1, g2, g3;                                          \
        expand32(g0, g1, lane);                                             \
        expand16(g0, g2, lane);                                             \
        expand16(g1, g3, lane);                                             \
        const float g4  = dppmov<0xB1>(g0);                                 \
        const float g5  = dppmov<0xB1>(g1);                                 \
        const float g6  = dppmov<0xB1>(g2);                                 \
        const float g7  = dppmov<0xB1>(g3);                                 \
        const float g8  = dppmov<0x4E>(g0);                                 \
        const float g9  = dppmov<0x4E>(g1);                                 \
        const float g10 = dppmov<0x4E>(g2);                                 \
        const float g11 = dppmov<0x4E>(g3);                                 \
        const float g12 = dppmov<0x4E>(g4);                                 \
        const float g13 = dppmov<0x4E>(g5);                                 \
        const float g14 = dppmov<0x4E>(g6);                                 \
        const float g15 = dppmov<0x4E>(g7);                                 \
        v2f a0lo = {0.f, 0.f}, a1lo = {0.f, 0.f};                           \
        v2f a0hi = {0.f, 0.f}, a1hi = {0.f, 0.f};                           \
        MAC(0,  g0,  lo) MAC(1,  g1,  lo) MAC(2,  g2,  lo) MAC(3,  g3,  lo) \
        MAC(4,  g4,  lo) MAC(5,  g5,  lo) MAC(6,  g6,  lo) MAC(7,  g7,  lo) \
        MAC(8,  g8,  hi) MAC(9,  g9,  hi) MAC(10, g10, hi) MAC(11, g11, hi) \
        MAC(12, g12, hi) MAC(13, g13, hi) MAC(14, g14, hi) MAC(15, g15, hi) \
        v2f a0 = a0lo + a0hi;                                               \
        v2f a1 = a1lo + a1hi;                                               \
        a0.x += dppmov<0x124>(a0.x); a0.y += dppmov<0x124>(a0.y);           \
        a1.x += dppmov<0x124>(a1.x); a1.y += dppmov<0x124>(a1.y);           \
        a0.x += dppmov<0x128>(a0.x); a0.y += dppmov<0x128>(a0.y);           \
        a1.x += dppmov<0x128>(a1.x); a1.y += dppmov<0x128>(a1.y);           \
        const float o01 = sel4 ? a0.y : a0.x;                               \
        const float o23 = sel4 ? a1.y : a1.x;                               \
        st = (sel8 ? o23 : o01) * (EX);                                     \
    }

    #define RENORM()                                                        \
    {                                                                       \
        int sb = lane0_bits(st);                                            \
        int e  = (sb >> 23) & 0xff;                                         \
        kexp  += e - 127;                                                   \
        st    *= __int_as_float((254 - e) << 23);                           \
    }

    // ---- scan: PF-step chunks, x prefetch, renorm per chunk ----
    float xpf[PF];
    #pragma unroll
    for (int k = 0; k < PF; ++k) {
        int idx = base + dir * k;
        if (idx < 0) idx = 0;
        xpf[k] = sx[(size_t)idx * CT];
    }
    int k = 0;
    while (k + PF <= count) {
        float exk[PF];
        #pragma unroll
        for (int j = 0; j < PF; ++j) exk[j] = __expf(xpf[j]);
        #pragma unroll
        for (int j = 0; j < PF; ++j) {
            int idx = base + dir * (k + PF + j);
            if (idx < 0) idx = 0;
            xpf[j] = sx[(size_t)idx * CT];
        }
        RENORM();
        STEP(exk[0]); STEP(exk[1]); STEP(exk[2]); STEP(exk[3]);
        k += PF;
    }
    for (int r = 0; k < count; ++k, ++r) {
        float e = __expf(xpf[r]);
        RENORM();
        STEP(e);
    }
    // bwd epilogue: B_tm = E * C_{tm+1} (no exp(x) factor)
    if (w == 1 && len >= 2) { RENORM(); STEP(1.0f); }
    RENORM();
    #undef STEP
    #undef MAC
    #undef RENORM

    // ---- combine across waves ----
    if (w == 0) sA[lane] = (lane < CT) ? st : 0.0f;
    else        sB[lane] = (lane < CT) ? st : 0.0f;
    if (lane == 0) sLZ[w] = (float)kexp * 0.6931471805599453f;
    __syncthreads();

    // numerator: gold-path score, all 128 threads
    const int* trow = tags + (size_t)b * CS;
    float nsum = 0.0f;
    for (int t = tid; t < CS; t += 128) {
        if (t < len) {
            int tg = trow[t];
            nsum += srow[(size_t)t * CT + tg];
            if (t >= 1) nsum += sTrans[trow[t - 1] * CT + tg];
        }
    }
    #pragma unroll
    for (int off = 32; off; off >>= 1) nsum += __shfl_xor(nsum, off);
    if (lane == 0) sN[w] = nsum;

    float den = 0.0f;
    if (w == 0) {
        float vp = sA[lane] * sB[lane];
        #pragma unroll
        for (int off = 32; off; off >>= 1) vp += __shfl_xor(vp, off);
        den = sLZ[0] + sLZ[1] + __logf(vp);
    }
    __syncthreads();

    if (tid == 0) {
        float num = sN[0] + sN[1] + start_tr[trow[0]] + end_tr[trow[len - 1]];
        atomicAdd(out, (den - num) * (1.0f / CB));
    }
}

extern "C" void kernel_launch(void* const* d_in, const int* in_sizes, int n_in,
                              void* d_out, int out_size, void* d_ws, size_t ws_size,
                              hipStream_t stream) {
    const float* scores   = (const float*)d_in[0];
    const int*   tags     = (const int*)d_in[1];
    const int*   mask     = (const int*)d_in[2];
    const float* trans    = (const float*)d_in[3];
    const float* start_tr = (const float*)d_in[4];
    const float* end_tr   = (const float*)d_in[5];
    float* out = (float*)d_out;

    zero_out_kernel<<<1, 1, 0, stream>>>(out);
    crf_scan_kernel<<<CB, 128, 0, stream>>>(scores, tags, mask, trans,
                                            start_tr, end_tr, out);
}